// Round 3
// baseline (1735.040 us; speedup 1.0000x reference)
//
#include <hip/hip_runtime.h>

#define N_NODES 100000
#define N_EDGES 600000
#define DIM 128

typedef unsigned short ushortT;
typedef __attribute__((ext_vector_type(8))) short short8;
typedef __attribute__((ext_vector_type(8))) float float8;
typedef __attribute__((ext_vector_type(4))) float float4v;
typedef __attribute__((ext_vector_type(4))) unsigned int uint4v;

__device__ __forceinline__ float bf2f(ushortT h) {
    return __builtin_bit_cast(float, ((unsigned int)h) << 16);
}
__device__ __forceinline__ ushortT f2bf(float f) {  // RNE
    unsigned int x = __builtin_bit_cast(unsigned int, f);
    unsigned int r = (x + 0x7fffu + ((x >> 16) & 1u)) >> 16;
    return (ushortT)r;
}

// ---- prep: W (128x128 f32, row-major KxN) -> transposed+swizzled bf16 hi/lo images
// element (k,n) stored at  n*128 + (((k>>3) ^ (n&15))<<3) + (k&7)
__global__ __launch_bounds__(256) void prep_kernel(const float* __restrict__ W1,
                                                   const float* __restrict__ W2,
                                                   ushortT* __restrict__ wt) {
    const float* Wf = (blockIdx.x == 0) ? W1 : W2;
    ushortT* outh = wt + blockIdx.x * 2 * 16384;
    ushortT* outl = outh + 16384;
    int t = threadIdx.x;
#pragma unroll
    for (int i = 0; i < 16; i++) {
        int c = t + i * 256;            // 0..4095
        int k = c >> 5;
        int n0 = (c & 31) * 4;
        float4v w = *(const float4v*)(Wf + k * 128 + n0);
        int g = k >> 3, kk = k & 7;
#pragma unroll
        for (int j = 0; j < 4; j++) {
            int n = n0 + j;
            ushortT wh = f2bf(w[j]);
            ushortT wl = f2bf(w[j] - bf2f(wh));
            int addr = n * 128 + (((g) ^ (n & 15)) << 3) + kk;
            outh[addr] = wh;
            outl[addr] = wl;
        }
    }
}

// z = x (f32 copy)
__global__ __launch_bounds__(256) void initz_kernel(const float* __restrict__ x,
                                                    float* __restrict__ z) {
    int i = blockIdx.x * 256 + threadIdx.x;
    ((float4v*)z)[i] = ((const float4v*)x)[i];
}

// one wave per edge: gather f32 row h[src], atomicAdd into z[dst]
__global__ __launch_bounds__(256) void scatter_kernel(const float* __restrict__ h,
                                                      const int* __restrict__ src,
                                                      const int* __restrict__ dst,
                                                      float* __restrict__ z) {
    int e = blockIdx.x * 4 + (threadIdx.x >> 6);
    if (e >= N_EDGES) return;
    int lane = threadIdx.x & 63;
    int s = src[e], d = dst[e];
    float2 v = *(const float2*)(h + (size_t)s * DIM + lane * 2);
    float* zp = z + (size_t)d * DIM + lane * 2;
    atomicAdd(zp, v.x);
    atomicAdd(zp + 1, v.y);
}

// GEMM: out = act(A @ W + bias), K=N=128, 3-term bf16-split for ~f32 accuracy.
// AMODE 0: A = a0 f32 (split inline). AMODE 1: A = a0/a1 bf16 hi/lo planes.
// OMODE 0: write hi/lo bf16 planes (o0,o1). OMODE 1: f32 to o0 AND o1. OMODE 2: f32 to o0.
template <int AMODE, bool RELU, int OMODE>
__global__ __launch_bounds__(256) void gemm_kernel(const void* __restrict__ a0,
                                                   const void* __restrict__ a1,
                                                   const ushortT* __restrict__ wt,  // hi at 0, lo at +16384
                                                   const float* __restrict__ bias,
                                                   void* __restrict__ o0,
                                                   void* __restrict__ o1) {
    __shared__ ushortT WH[16384];
    __shared__ ushortT WL[16384];
    {   // copy pre-swizzled images: coalesced 16B, conflict-free LDS
        int t = threadIdx.x;
#pragma unroll
        for (int i = 0; i < 8; i++) {
            int idx = (t + i * 256) * 8;  // element index, 16B granule
            *(uint4v*)&WH[idx] = *(const uint4v*)&wt[idx];
            *(uint4v*)&WL[idx] = *(const uint4v*)&wt[16384 + idx];
        }
    }
    __syncthreads();

    int wid = threadIdx.x >> 6, lane = threadIdx.x & 63;
    int unit = blockIdx.x * 4 + wid;  // 32 rows per wave
    if (unit * 32 >= N_NODES) return;
    int row0 = unit * 32;
    int quad = lane >> 4;
    int col16 = lane & 15;

    float bia[8];
#pragma unroll
    for (int n = 0; n < 8; n++) bia[n] = bias[n * 16 + col16];

    float4v acc[2][8];
#pragma unroll
    for (int r = 0; r < 2; r++)
#pragma unroll
        for (int n = 0; n < 8; n++) acc[r][n] = (float4v)0.0f;

#pragma unroll
    for (int s = 0; s < 4; s++) {
        short8 bh[8], bl[8];
#pragma unroll
        for (int n = 0; n < 8; n++) {
            int addr = (n * 16 + col16) * 128 + (((s * 4 + quad) ^ col16) << 3);
            bh[n] = *(const short8*)&WH[addr];
            bl[n] = *(const short8*)&WL[addr];
        }
#pragma unroll
        for (int r = 0; r < 2; r++) {
            size_t arow = (size_t)(row0 + r * 16 + col16);
            short8 ah, al;
            if constexpr (AMODE == 0) {
                const float* A = (const float*)a0;
                float8 af = *(const float8*)(A + arow * 128 + s * 32 + quad * 8);
                ushortT ahh[8], all[8];
#pragma unroll
                for (int j = 0; j < 8; j++) {
                    ushortT h = f2bf(af[j]);
                    ahh[j] = h;
                    all[j] = f2bf(af[j] - bf2f(h));
                }
                ah = *(short8*)ahh;
                al = *(short8*)all;
            } else {
                const ushortT* Ah = (const ushortT*)a0;
                const ushortT* Al = (const ushortT*)a1;
                ah = *(const short8*)(Ah + arow * 128 + s * 32 + quad * 8);
                al = *(const short8*)(Al + arow * 128 + s * 32 + quad * 8);
            }
#pragma unroll
            for (int n = 0; n < 8; n++) {
                acc[r][n] = __builtin_amdgcn_mfma_f32_16x16x32_bf16(ah, bh[n], acc[r][n], 0, 0, 0);
                acc[r][n] = __builtin_amdgcn_mfma_f32_16x16x32_bf16(al, bh[n], acc[r][n], 0, 0, 0);
                acc[r][n] = __builtin_amdgcn_mfma_f32_16x16x32_bf16(ah, bl[n], acc[r][n], 0, 0, 0);
            }
        }
    }

    // epilogue: C/D layout col=lane&15, row=quad*4+reg
#pragma unroll
    for (int r = 0; r < 2; r++) {
#pragma unroll
        for (int i = 0; i < 4; i++) {
            size_t row = (size_t)(row0 + r * 16 + quad * 4 + i);
#pragma unroll
            for (int n = 0; n < 8; n++) {
                float v = acc[r][n][i] + bia[n];
                if (RELU) v = v > 0.0f ? v : 0.0f;
                int col = n * 16 + col16;
                if constexpr (OMODE == 0) {
                    ushortT hi = f2bf(v);
                    ((ushortT*)o0)[row * 128 + col] = hi;
                    ((ushortT*)o1)[row * 128 + col] = f2bf(v - bf2f(hi));
                } else if constexpr (OMODE == 1) {
                    ((float*)o0)[row * 128 + col] = v;
                    ((float*)o1)[row * 128 + col] = v;
                } else {
                    ((float*)o0)[row * 128 + col] = v;
                }
            }
        }
    }
}

extern "C" void kernel_launch(void* const* d_in, const int* in_sizes, int n_in,
                              void* d_out, int out_size, void* d_ws, size_t ws_size,
                              hipStream_t stream) {
    const float* x  = (const float*)d_in[0];
    const int* src  = (const int*)d_in[1];
    const int* dst  = (const int*)d_in[2];
    const float* W1 = (const float*)d_in[3];
    const float* b1 = (const float*)d_in[4];
    const float* W2 = (const float*)d_in[5];
    const float* b2 = (const float*)d_in[6];

    float* zbuf = (float*)d_out;  // d_out doubles as the f32 z accumulator (51.2MB)

    char* ws = (char*)d_ws;
    ushortT* wt1   = (ushortT*)ws;                       // 64 KB (hi+lo)
    ushortT* wt2   = wt1 + 2 * 16384;                    // 64 KB
    ushortT* hidhi = (ushortT*)(ws + 131072);            // 25.6 MB
    ushortT* hidlo = (ushortT*)(ws + 131072 + 25600000); // 25.6 MB
    float*   hbuf  = (float*)(ws + 131072 + 51200000);   // 51.2 MB
    // total ~102.5 MB

    dim3 blk(256);
    const int gInit = N_NODES * DIM / 4 / 256;  // 12500 exact
    const int gScat = N_EDGES / 4;              // 150000 exact
    const int gGemm = (N_NODES / 32 + 3) / 4;   // 782

    prep_kernel<<<2, blk, 0, stream>>>(W1, W2, wt1);
    // layer 0
    initz_kernel<<<gInit, blk, 0, stream>>>(x, zbuf);
    scatter_kernel<<<gScat, blk, 0, stream>>>(x, src, dst, zbuf);
    gemm_kernel<0, true, 0><<<gGemm, blk, 0, stream>>>(zbuf, nullptr, wt1, b1, hidhi, hidlo);
    gemm_kernel<1, true, 1><<<gGemm, blk, 0, stream>>>(hidhi, hidlo, wt2, b2, hbuf, zbuf);
    // layer 1 (z already = h1 via OMODE 1)
    scatter_kernel<<<gScat, blk, 0, stream>>>(hbuf, src, dst, zbuf);
    gemm_kernel<0, true, 0><<<gGemm, blk, 0, stream>>>(zbuf, nullptr, wt1, b1, hidhi, hidlo);
    gemm_kernel<1, true, 1><<<gGemm, blk, 0, stream>>>(hidhi, hidlo, wt2, b2, hbuf, zbuf);
    // layer 2: final (no inter-layer relu on output)
    scatter_kernel<<<gScat, blk, 0, stream>>>(hbuf, src, dst, zbuf);
    gemm_kernel<0, true, 0><<<gGemm, blk, 0, stream>>>(zbuf, nullptr, wt1, b1, hidhi, hidlo);
    gemm_kernel<1, false, 2><<<gGemm, blk, 0, stream>>>(hidhi, hidlo, wt2, b2, (float*)d_out, nullptr);
}

// Round 4
// 573.777 us; speedup vs baseline: 3.0239x; 3.0239x over previous
//
#include <hip/hip_runtime.h>

#define N_NODES 100000
#define N_EDGES 600000
#define DIM 128

typedef unsigned short ushortT;
typedef __attribute__((ext_vector_type(8))) short short8;
typedef __attribute__((ext_vector_type(8))) float float8;
typedef __attribute__((ext_vector_type(4))) float float4v;
typedef __attribute__((ext_vector_type(4))) unsigned int uint4v;

__device__ __forceinline__ float bf2f(ushortT h) {
    return __builtin_bit_cast(float, ((unsigned int)h) << 16);
}
__device__ __forceinline__ ushortT f2bf(float f) {  // RNE
    unsigned int x = __builtin_bit_cast(unsigned int, f);
    unsigned int r = (x + 0x7fffu + ((x >> 16) & 1u)) >> 16;
    return (ushortT)r;
}

// ---- prep: W (128x128 f32, row-major KxN) -> transposed+swizzled bf16 hi/lo images
// element (k,n) stored at  n*128 + (((k>>3) ^ (n&15))<<3) + (k&7)
__global__ __launch_bounds__(256) void prep_kernel(const float* __restrict__ W1,
                                                   const float* __restrict__ W2,
                                                   ushortT* __restrict__ wt) {
    const float* Wf = (blockIdx.x == 0) ? W1 : W2;
    ushortT* outh = wt + blockIdx.x * 2 * 16384;
    ushortT* outl = outh + 16384;
    int t = threadIdx.x;
#pragma unroll
    for (int i = 0; i < 16; i++) {
        int c = t + i * 256;            // 0..4095
        int k = c >> 5;
        int n0 = (c & 31) * 4;
        float4v w = *(const float4v*)(Wf + k * 128 + n0);
        int g = k >> 3, kk = k & 7;
#pragma unroll
        for (int j = 0; j < 4; j++) {
            int n = n0 + j;
            ushortT wh = f2bf(w[j]);
            ushortT wl = f2bf(w[j] - bf2f(wh));
            int addr = n * 128 + (((g) ^ (n & 15)) << 3) + kk;
            outh[addr] = wh;
            outl[addr] = wl;
        }
    }
}

// ---- CSR build (same graph every call; rebuilt per call for harness purity) ----
__global__ __launch_bounds__(256) void hist_kernel(const int* __restrict__ dst,
                                                   int* __restrict__ counts) {
    int e = blockIdx.x * 256 + threadIdx.x;
    if (e < N_EDGES) atomicAdd(&counts[dst[e]], 1);
}

// single-block exclusive scan of counts[N_NODES] -> offsets[N_NODES+1]; cursor=offsets copy
__global__ __launch_bounds__(1024) void scan_kernel(int* __restrict__ counts_cursor,
                                                    int* __restrict__ offsets) {
    __shared__ int wsum[16];
    int tid = threadIdx.x, lane = tid & 63, wid = tid >> 6;
    int carry = 0;
    const int CHUNKS = (N_NODES + 1024) / 1024 + 1;  // 98 covers i == N_NODES
    for (int chunk = 0; chunk < CHUNKS; ++chunk) {
        int i = chunk * 1024 + tid;
        int v = (i < N_NODES) ? counts_cursor[i] : 0;
        int incl = v;
#pragma unroll
        for (int off = 1; off < 64; off <<= 1) {
            int u = __shfl_up(incl, off);
            if (lane >= off) incl += u;
        }
        if (lane == 63) wsum[wid] = incl;
        __syncthreads();
        if (wid == 0) {
            int s = (lane < 16) ? wsum[lane] : 0;
#pragma unroll
            for (int off = 1; off < 16; off <<= 1) {
                int u = __shfl_up(s, off);
                if (lane >= off) s += u;
            }
            if (lane < 16) wsum[lane] = s;  // inclusive wave sums
        }
        __syncthreads();
        int wexcl = (wid == 0) ? 0 : wsum[wid - 1];
        int total = wsum[15];
        int excl = carry + wexcl + incl - v;
        if (i <= N_NODES) offsets[i] = excl;
        if (i < N_NODES) counts_cursor[i] = excl;  // cursor for fill
        carry += total;
        __syncthreads();
    }
}

__global__ __launch_bounds__(256) void fill_kernel(const int* __restrict__ src,
                                                   const int* __restrict__ dst,
                                                   int* __restrict__ cursor,
                                                   int* __restrict__ eidx) {
    int e = blockIdx.x * 256 + threadIdx.x;
    if (e < N_EDGES) {
        int pos = atomicAdd(&cursor[dst[e]], 1);
        eidx[pos] = src[e];
    }
}

// ---- aggregation: one wave per node; z[v] = h[v] + sum_{e in CSR[v]} h[eidx[e]] ----
__global__ __launch_bounds__(256) void agg_kernel(const float* __restrict__ h,
                                                  const int* __restrict__ offsets,
                                                  const int* __restrict__ eidx,
                                                  float* __restrict__ z) {
    int w = blockIdx.x * 4 + (threadIdx.x >> 6);  // node id; grid exact (25000 blocks)
    w = __builtin_amdgcn_readfirstlane(w);
    int lane = threadIdx.x & 63;
    int beg = offsets[w], end = offsets[w + 1];
    float2 acc = *(const float2*)(h + (size_t)w * DIM + lane * 2);
    for (int i = beg; i < end; ++i) {
        int s = eidx[i];
        float2 v = *(const float2*)(h + (size_t)s * DIM + lane * 2);
        acc.x += v.x;
        acc.y += v.y;
    }
    *(float2*)(z + (size_t)w * DIM + lane * 2) = acc;
}

// GEMM: out = act(A @ W + bias), K=N=128, 3-term bf16-split for ~f32 accuracy.
// AMODE 0: A = a0 f32 (split inline). AMODE 1: A = a0/a1 bf16 hi/lo planes.
// OMODE 0: write hi/lo bf16 planes (o0,o1). OMODE 2: f32 to o0.
template <int AMODE, bool RELU, int OMODE>
__global__ __launch_bounds__(256) void gemm_kernel(const void* __restrict__ a0,
                                                   const void* __restrict__ a1,
                                                   const ushortT* __restrict__ wt,  // hi at 0, lo at +16384
                                                   const float* __restrict__ bias,
                                                   void* __restrict__ o0,
                                                   void* __restrict__ o1) {
    __shared__ ushortT WH[16384];
    __shared__ ushortT WL[16384];
    {   // copy pre-swizzled images: coalesced 16B, conflict-free LDS
        int t = threadIdx.x;
#pragma unroll
        for (int i = 0; i < 8; i++) {
            int idx = (t + i * 256) * 8;  // element index, 16B granule
            *(uint4v*)&WH[idx] = *(const uint4v*)&wt[idx];
            *(uint4v*)&WL[idx] = *(const uint4v*)&wt[16384 + idx];
        }
    }
    __syncthreads();

    int wid = threadIdx.x >> 6, lane = threadIdx.x & 63;
    int unit = blockIdx.x * 4 + wid;  // 32 rows per wave
    if (unit * 32 >= N_NODES) return;
    int row0 = unit * 32;
    int quad = lane >> 4;
    int col16 = lane & 15;

    float bia[8];
#pragma unroll
    for (int n = 0; n < 8; n++) bia[n] = bias[n * 16 + col16];

    float4v acc[2][8];
#pragma unroll
    for (int r = 0; r < 2; r++)
#pragma unroll
        for (int n = 0; n < 8; n++) acc[r][n] = (float4v)0.0f;

#pragma unroll
    for (int s = 0; s < 4; s++) {
        short8 bh[8], bl[8];
#pragma unroll
        for (int n = 0; n < 8; n++) {
            int addr = (n * 16 + col16) * 128 + (((s * 4 + quad) ^ col16) << 3);
            bh[n] = *(const short8*)&WH[addr];
            bl[n] = *(const short8*)&WL[addr];
        }
#pragma unroll
        for (int r = 0; r < 2; r++) {
            size_t arow = (size_t)(row0 + r * 16 + col16);
            short8 ah, al;
            if constexpr (AMODE == 0) {
                const float* A = (const float*)a0;
                float8 af = *(const float8*)(A + arow * 128 + s * 32 + quad * 8);
                ushortT ahh[8], all[8];
#pragma unroll
                for (int j = 0; j < 8; j++) {
                    ushortT h = f2bf(af[j]);
                    ahh[j] = h;
                    all[j] = f2bf(af[j] - bf2f(h));
                }
                ah = *(short8*)ahh;
                al = *(short8*)all;
            } else {
                const ushortT* Ah = (const ushortT*)a0;
                const ushortT* Al = (const ushortT*)a1;
                ah = *(const short8*)(Ah + arow * 128 + s * 32 + quad * 8);
                al = *(const short8*)(Al + arow * 128 + s * 32 + quad * 8);
            }
#pragma unroll
            for (int n = 0; n < 8; n++) {
                acc[r][n] = __builtin_amdgcn_mfma_f32_16x16x32_bf16(ah, bh[n], acc[r][n], 0, 0, 0);
                acc[r][n] = __builtin_amdgcn_mfma_f32_16x16x32_bf16(al, bh[n], acc[r][n], 0, 0, 0);
                acc[r][n] = __builtin_amdgcn_mfma_f32_16x16x32_bf16(ah, bl[n], acc[r][n], 0, 0, 0);
            }
        }
    }

    // epilogue: C/D layout col=lane&15, row=quad*4+reg
#pragma unroll
    for (int r = 0; r < 2; r++) {
#pragma unroll
        for (int i = 0; i < 4; i++) {
            size_t row = (size_t)(row0 + r * 16 + quad * 4 + i);
#pragma unroll
            for (int n = 0; n < 8; n++) {
                float v = acc[r][n][i] + bia[n];
                if (RELU) v = v > 0.0f ? v : 0.0f;
                int col = n * 16 + col16;
                if constexpr (OMODE == 0) {
                    ushortT hi = f2bf(v);
                    ((ushortT*)o0)[row * 128 + col] = hi;
                    ((ushortT*)o1)[row * 128 + col] = f2bf(v - bf2f(hi));
                } else {
                    ((float*)o0)[row * 128 + col] = v;
                }
            }
        }
    }
}

extern "C" void kernel_launch(void* const* d_in, const int* in_sizes, int n_in,
                              void* d_out, int out_size, void* d_ws, size_t ws_size,
                              hipStream_t stream) {
    const float* x  = (const float*)d_in[0];
    const int* src  = (const int*)d_in[1];
    const int* dst  = (const int*)d_in[2];
    const float* W1 = (const float*)d_in[3];
    const float* b1 = (const float*)d_in[4];
    const float* W2 = (const float*)d_in[5];
    const float* b2 = (const float*)d_in[6];

    float* zbuf = (float*)d_out;  // d_out doubles as the f32 z buffer (51.2MB)

    char* ws = (char*)d_ws;
    ushortT* wt1    = (ushortT*)ws;                        // 64 KB (hi+lo)
    ushortT* wt2    = wt1 + 2 * 16384;                     // 64 KB
    int*     offs   = (int*)(ws + 131072);                 // 100001 ints (~400KB)
    int*     cursor = (int*)(ws + 531328);                 // 100000 ints (counts/cursor)
    int*     eidx   = (int*)(ws + 931328);                 // 600000 ints (2.4MB)
    ushortT* hidhi  = (ushortT*)(ws + 3331328);            // 25.6 MB
    ushortT* hidlo  = (ushortT*)(ws + 28931328);           // 25.6 MB
    float*   hbuf   = (float*)(ws + 54531328);             // 51.2 MB
    // total ~105.8 MB

    dim3 blk(256);
    const int gEdge = (N_EDGES + 255) / 256;    // 2344
    const int gAgg  = N_NODES / 4;              // 25000 exact (1 wave/node)
    const int gGemm = (N_NODES / 32 + 3) / 4;   // 782

    // weights prep + CSR build (per call; graph is identical every call)
    prep_kernel<<<2, blk, 0, stream>>>(W1, W2, wt1);
    hipMemsetAsync(cursor, 0, N_NODES * sizeof(int), stream);
    hist_kernel<<<gEdge, blk, 0, stream>>>(dst, cursor);
    scan_kernel<<<1, 1024, 0, stream>>>(cursor, offs);
    fill_kernel<<<gEdge, blk, 0, stream>>>(src, dst, cursor, eidx);

    // layer 0
    agg_kernel<<<gAgg, blk, 0, stream>>>(x, offs, eidx, zbuf);
    gemm_kernel<0, true, 0><<<gGemm, blk, 0, stream>>>(zbuf, nullptr, wt1, b1, hidhi, hidlo);
    gemm_kernel<1, true, 2><<<gGemm, blk, 0, stream>>>(hidhi, hidlo, wt2, b2, hbuf, nullptr);
    // layer 1
    agg_kernel<<<gAgg, blk, 0, stream>>>(hbuf, offs, eidx, zbuf);
    gemm_kernel<0, true, 0><<<gGemm, blk, 0, stream>>>(zbuf, nullptr, wt1, b1, hidhi, hidlo);
    gemm_kernel<1, true, 2><<<gGemm, blk, 0, stream>>>(hidhi, hidlo, wt2, b2, hbuf, nullptr);
    // layer 2 (final: no trailing relu)
    agg_kernel<<<gAgg, blk, 0, stream>>>(hbuf, offs, eidx, zbuf);
    gemm_kernel<0, true, 0><<<gGemm, blk, 0, stream>>>(zbuf, nullptr, wt1, b1, hidhi, hidlo);
    gemm_kernel<1, false, 2><<<gGemm, blk, 0, stream>>>(hidhi, hidlo, wt2, b2, (float*)d_out, nullptr);
}

// Round 5
// 489.924 us; speedup vs baseline: 3.5414x; 1.1712x over previous
//
#include <hip/hip_runtime.h>

#define N_NODES 100000
#define N_EDGES 600000
#define DIM 128

typedef unsigned short ushortT;
typedef __attribute__((ext_vector_type(8))) short short8;
typedef __attribute__((ext_vector_type(8))) float float8;
typedef __attribute__((ext_vector_type(4))) float float4v;
typedef __attribute__((ext_vector_type(4))) unsigned int uint4v;

__device__ __forceinline__ float bf2f(ushortT h) {
    return __builtin_bit_cast(float, ((unsigned int)h) << 16);
}
__device__ __forceinline__ ushortT f2bf(float f) {  // RNE
    unsigned int x = __builtin_bit_cast(unsigned int, f);
    unsigned int r = (x + 0x7fffu + ((x >> 16) & 1u)) >> 16;
    return (ushortT)r;
}

// ---- prep: W (128x128 f32, row-major KxN) -> transposed+swizzled bf16 hi/lo images
// element (k,n) stored at  n*128 + (((k>>3) ^ (n&15))<<3) + (k&7)
__global__ __launch_bounds__(256) void prep_kernel(const float* __restrict__ W1,
                                                   const float* __restrict__ W2,
                                                   ushortT* __restrict__ wt) {
    const float* Wf = (blockIdx.x == 0) ? W1 : W2;
    ushortT* outh = wt + blockIdx.x * 2 * 16384;
    ushortT* outl = outh + 16384;
    int t = threadIdx.x;
#pragma unroll
    for (int i = 0; i < 16; i++) {
        int c = t + i * 256;            // 0..4095
        int k = c >> 5;
        int n0 = (c & 31) * 4;
        float4v w = *(const float4v*)(Wf + k * 128 + n0);
        int g = k >> 3, kk = k & 7;
#pragma unroll
        for (int j = 0; j < 4; j++) {
            int n = n0 + j;
            ushortT wh = f2bf(w[j]);
            ushortT wl = f2bf(w[j] - bf2f(wh));
            int addr = n * 128 + (((g) ^ (n & 15)) << 3) + kk;
            outh[addr] = wh;
            outl[addr] = wl;
        }
    }
}

// ---- CSR build (same graph every call; rebuilt per call for harness purity) ----
__global__ __launch_bounds__(256) void hist_kernel(const int* __restrict__ dst,
                                                   int* __restrict__ counts) {
    int e = blockIdx.x * 256 + threadIdx.x;
    if (e < N_EDGES) atomicAdd(&counts[dst[e]], 1);
}

#define SCAN_BLOCKS 98  // 98*1024 >= 100000

// per-block exclusive scan of counts -> local, block totals -> bsums
__global__ __launch_bounds__(1024) void blockscan_kernel(const int* __restrict__ counts,
                                                         int* __restrict__ local,
                                                         int* __restrict__ bsums) {
    __shared__ int wsum[16];
    int tid = threadIdx.x, lane = tid & 63, wid = tid >> 6;
    int i = blockIdx.x * 1024 + tid;
    int v = (i < N_NODES) ? counts[i] : 0;
    int incl = v;
#pragma unroll
    for (int off = 1; off < 64; off <<= 1) {
        int u = __shfl_up(incl, off);
        if (lane >= off) incl += u;
    }
    if (lane == 63) wsum[wid] = incl;
    __syncthreads();
    if (wid == 0) {
        int s = (lane < 16) ? wsum[lane] : 0;
#pragma unroll
        for (int off = 1; off < 16; off <<= 1) {
            int u = __shfl_up(s, off);
            if (lane >= off) s += u;
        }
        if (lane < 16) wsum[lane] = s;  // inclusive wave sums
    }
    __syncthreads();
    int excl = ((wid == 0) ? 0 : wsum[wid - 1]) + incl - v;
    if (i < N_NODES) local[i] = excl;
    if (tid == 0) bsums[blockIdx.x] = wsum[15];
}

// add cross-block base; write final offsets + cursor copy; offsets[N] = E (known constant)
__global__ __launch_bounds__(1024) void fixup_kernel(const int* __restrict__ local,
                                                     const int* __restrict__ bsums,
                                                     int* __restrict__ offsets,
                                                     int* __restrict__ cursor) {
    __shared__ int sbase;
    int tid = threadIdx.x;
    if (tid < 64) {
        int s = 0;
        for (int j = tid; j < blockIdx.x; j += 64) s += bsums[j];
#pragma unroll
        for (int off = 32; off >= 1; off >>= 1) s += __shfl_xor(s, off);
        if (tid == 0) sbase = s;
    }
    __syncthreads();
    int base = sbase;
    int i = blockIdx.x * 1024 + tid;
    if (i < N_NODES) {
        int o = local[i] + base;
        offsets[i] = o;
        cursor[i] = o;
    }
    if (blockIdx.x == 0 && tid == 0) offsets[N_NODES] = N_EDGES;
}

__global__ __launch_bounds__(256) void fill_kernel(const int* __restrict__ src,
                                                   const int* __restrict__ dst,
                                                   int* __restrict__ cursor,
                                                   int* __restrict__ eidx) {
    int e = blockIdx.x * 256 + threadIdx.x;
    if (e < N_EDGES) {
        int pos = atomicAdd(&cursor[dst[e]], 1);
        eidx[pos] = src[e];
    }
}

// ---- aggregation: one wave per node; z[v] = h[v] + sum_{e in CSR[v]} h[eidx[e]] ----
__global__ __launch_bounds__(256) void agg_kernel(const float* __restrict__ h,
                                                  const int* __restrict__ offsets,
                                                  const int* __restrict__ eidx,
                                                  float* __restrict__ z) {
    int w = blockIdx.x * 4 + (threadIdx.x >> 6);  // node id; grid exact (25000 blocks)
    w = __builtin_amdgcn_readfirstlane(w);
    int lane = threadIdx.x & 63;
    int beg = offsets[w], end = offsets[w + 1];
    float2 acc = *(const float2*)(h + (size_t)w * DIM + lane * 2);
    for (int i = beg; i < end; ++i) {
        int s = eidx[i];
        float2 v = *(const float2*)(h + (size_t)s * DIM + lane * 2);
        acc.x += v.x;
        acc.y += v.y;
    }
    *(float2*)(z + (size_t)w * DIM + lane * 2) = acc;
}

// GEMM: out = act(A @ W + bias), K=N=128, 3-term bf16-split for ~f32 accuracy.
// AMODE 0: A = a0 f32 (split inline). AMODE 1: A = a0/a1 bf16 hi/lo planes.
// OMODE 0: write hi/lo bf16 planes (o0,o1). OMODE 2: f32 to o0.
template <int AMODE, bool RELU, int OMODE>
__global__ __launch_bounds__(256) void gemm_kernel(const void* __restrict__ a0,
                                                   const void* __restrict__ a1,
                                                   const ushortT* __restrict__ wt,  // hi at 0, lo at +16384
                                                   const float* __restrict__ bias,
                                                   void* __restrict__ o0,
                                                   void* __restrict__ o1) {
    __shared__ ushortT WH[16384];
    __shared__ ushortT WL[16384];
    {   // copy pre-swizzled images: coalesced 16B, conflict-free LDS
        int t = threadIdx.x;
#pragma unroll
        for (int i = 0; i < 8; i++) {
            int idx = (t + i * 256) * 8;  // element index, 16B granule
            *(uint4v*)&WH[idx] = *(const uint4v*)&wt[idx];
            *(uint4v*)&WL[idx] = *(const uint4v*)&wt[16384 + idx];
        }
    }
    __syncthreads();

    int wid = threadIdx.x >> 6, lane = threadIdx.x & 63;
    int unit = blockIdx.x * 4 + wid;  // 32 rows per wave
    if (unit * 32 >= N_NODES) return;
    int row0 = unit * 32;
    int quad = lane >> 4;
    int col16 = lane & 15;

    float bia[8];
#pragma unroll
    for (int n = 0; n < 8; n++) bia[n] = bias[n * 16 + col16];

    float4v acc[2][8];
#pragma unroll
    for (int r = 0; r < 2; r++)
#pragma unroll
        for (int n = 0; n < 8; n++) acc[r][n] = (float4v)0.0f;

#pragma unroll
    for (int s = 0; s < 4; s++) {
        short8 bh[8], bl[8];
#pragma unroll
        for (int n = 0; n < 8; n++) {
            int addr = (n * 16 + col16) * 128 + (((s * 4 + quad) ^ col16) << 3);
            bh[n] = *(const short8*)&WH[addr];
            bl[n] = *(const short8*)&WL[addr];
        }
#pragma unroll
        for (int r = 0; r < 2; r++) {
            size_t arow = (size_t)(row0 + r * 16 + col16);
            short8 ah, al;
            if constexpr (AMODE == 0) {
                const float* A = (const float*)a0;
                float8 af = *(const float8*)(A + arow * 128 + s * 32 + quad * 8);
                ushortT ahh[8], all[8];
#pragma unroll
                for (int j = 0; j < 8; j++) {
                    ushortT h = f2bf(af[j]);
                    ahh[j] = h;
                    all[j] = f2bf(af[j] - bf2f(h));
                }
                ah = *(short8*)ahh;
                al = *(short8*)all;
            } else {
                const ushortT* Ah = (const ushortT*)a0;
                const ushortT* Al = (const ushortT*)a1;
                ah = *(const short8*)(Ah + arow * 128 + s * 32 + quad * 8);
                al = *(const short8*)(Al + arow * 128 + s * 32 + quad * 8);
            }
#pragma unroll
            for (int n = 0; n < 8; n++) {
                acc[r][n] = __builtin_amdgcn_mfma_f32_16x16x32_bf16(ah, bh[n], acc[r][n], 0, 0, 0);
                acc[r][n] = __builtin_amdgcn_mfma_f32_16x16x32_bf16(al, bh[n], acc[r][n], 0, 0, 0);
                acc[r][n] = __builtin_amdgcn_mfma_f32_16x16x32_bf16(ah, bl[n], acc[r][n], 0, 0, 0);
            }
        }
    }

    // epilogue: C/D layout col=lane&15, row=quad*4+reg
#pragma unroll
    for (int r = 0; r < 2; r++) {
#pragma unroll
        for (int i = 0; i < 4; i++) {
            size_t row = (size_t)(row0 + r * 16 + quad * 4 + i);
#pragma unroll
            for (int n = 0; n < 8; n++) {
                float v = acc[r][n][i] + bia[n];
                if (RELU) v = v > 0.0f ? v : 0.0f;
                int col = n * 16 + col16;
                if constexpr (OMODE == 0) {
                    ushortT hi = f2bf(v);
                    ((ushortT*)o0)[row * 128 + col] = hi;
                    ((ushortT*)o1)[row * 128 + col] = f2bf(v - bf2f(hi));
                } else {
                    ((float*)o0)[row * 128 + col] = v;
                }
            }
        }
    }
}

extern "C" void kernel_launch(void* const* d_in, const int* in_sizes, int n_in,
                              void* d_out, int out_size, void* d_ws, size_t ws_size,
                              hipStream_t stream) {
    const float* x  = (const float*)d_in[0];
    const int* src  = (const int*)d_in[1];
    const int* dst  = (const int*)d_in[2];
    const float* W1 = (const float*)d_in[3];
    const float* b1 = (const float*)d_in[4];
    const float* W2 = (const float*)d_in[5];
    const float* b2 = (const float*)d_in[6];

    float* zbuf = (float*)d_out;  // d_out doubles as the f32 z buffer (51.2MB)

    char* ws = (char*)d_ws;
    ushortT* wt1    = (ushortT*)ws;                        // 64 KB (hi+lo)
    ushortT* wt2    = wt1 + 2 * 16384;                     // 64 KB
    int*     offs   = (int*)(ws + 131072);                 // 100001 ints (~400KB)
    int*     cursor = (int*)(ws + 531328);                 // 100000 ints (counts/cursor)
    int*     eidx   = (int*)(ws + 931328);                 // 600000 ints (2.4MB)
    int*     local  = (int*)(ws + 3331328);                // 100000 ints (scan temp)
    int*     bsums  = (int*)(ws + 3731328);                // 98 ints
    ushortT* hidhi  = (ushortT*)(ws + 3731840);            // 25.6 MB
    ushortT* hidlo  = (ushortT*)(ws + 29331840);           // 25.6 MB
    float*   hbuf   = (float*)(ws + 54931840);             // 51.2 MB
    // total ~106.2 MB

    dim3 blk(256);
    const int gEdge = (N_EDGES + 255) / 256;    // 2344
    const int gAgg  = N_NODES / 4;              // 25000 exact (1 wave/node)
    const int gGemm = (N_NODES / 32 + 3) / 4;   // 782

    // weights prep + CSR build (per call; graph is identical every call)
    prep_kernel<<<2, blk, 0, stream>>>(W1, W2, wt1);
    hipMemsetAsync(cursor, 0, N_NODES * sizeof(int), stream);
    hist_kernel<<<gEdge, blk, 0, stream>>>(dst, cursor);
    blockscan_kernel<<<SCAN_BLOCKS, 1024, 0, stream>>>(cursor, local, bsums);
    fixup_kernel<<<SCAN_BLOCKS, 1024, 0, stream>>>(local, bsums, offs, cursor);
    fill_kernel<<<gEdge, blk, 0, stream>>>(src, dst, cursor, eidx);

    // layer 0
    agg_kernel<<<gAgg, blk, 0, stream>>>(x, offs, eidx, zbuf);
    gemm_kernel<0, true, 0><<<gGemm, blk, 0, stream>>>(zbuf, nullptr, wt1, b1, hidhi, hidlo);
    gemm_kernel<1, true, 2><<<gGemm, blk, 0, stream>>>(hidhi, hidlo, wt2, b2, hbuf, nullptr);
    // layer 1
    agg_kernel<<<gAgg, blk, 0, stream>>>(hbuf, offs, eidx, zbuf);
    gemm_kernel<0, true, 0><<<gGemm, blk, 0, stream>>>(zbuf, nullptr, wt1, b1, hidhi, hidlo);
    gemm_kernel<1, true, 2><<<gGemm, blk, 0, stream>>>(hidhi, hidlo, wt2, b2, hbuf, nullptr);
    // layer 2 (final: no trailing relu)
    agg_kernel<<<gAgg, blk, 0, stream>>>(hbuf, offs, eidx, zbuf);
    gemm_kernel<0, true, 0><<<gGemm, blk, 0, stream>>>(zbuf, nullptr, wt1, b1, hidhi, hidlo);
    gemm_kernel<1, false, 2><<<gGemm, blk, 0, stream>>>(hidhi, hidlo, wt2, b2, (float*)d_out, nullptr);
}

// Round 6
// 477.050 us; speedup vs baseline: 3.6370x; 1.0270x over previous
//
#include <hip/hip_runtime.h>

#define N_NODES 100000
#define N_EDGES 600000
#define DIM 128

typedef unsigned short ushortT;
typedef __attribute__((ext_vector_type(8))) short short8;
typedef __attribute__((ext_vector_type(4))) float float4v;
typedef __attribute__((ext_vector_type(4))) unsigned int uint4v;

__device__ __forceinline__ float bf2f(ushortT h) {
    return __builtin_bit_cast(float, ((unsigned int)h) << 16);
}
__device__ __forceinline__ ushortT f2bf(float f) {  // RNE
    unsigned int x = __builtin_bit_cast(unsigned int, f);
    unsigned int r = (x + 0x7fffu + ((x >> 16) & 1u)) >> 16;
    return (ushortT)r;
}
// pack two floats -> two bf16 (lo=a, hi=b) + residuals
__device__ __forceinline__ unsigned int pk_hi(float a, float b) {
    return (unsigned int)f2bf(a) | ((unsigned int)f2bf(b) << 16);
}

// ---- prep: W (128x128 f32, row-major KxN) -> transposed+swizzled bf16 hi/lo images
// element (k,n) stored at  n*128 + (((k>>3) ^ (n&15))<<3) + (k&7)
__global__ __launch_bounds__(256) void prep_kernel(const float* __restrict__ W1,
                                                   const float* __restrict__ W2,
                                                   ushortT* __restrict__ wt) {
    const float* Wf = (blockIdx.x == 0) ? W1 : W2;
    ushortT* outh = wt + blockIdx.x * 2 * 16384;
    ushortT* outl = outh + 16384;
    int t = threadIdx.x;
#pragma unroll
    for (int i = 0; i < 16; i++) {
        int c = t + i * 256;            // 0..4095
        int k = c >> 5;
        int n0 = (c & 31) * 4;
        float4v w = *(const float4v*)(Wf + k * 128 + n0);
        int g = k >> 3, kk = k & 7;
#pragma unroll
        for (int j = 0; j < 4; j++) {
            int n = n0 + j;
            ushortT wh = f2bf(w[j]);
            ushortT wl = f2bf(w[j] - bf2f(wh));
            int addr = n * 128 + (((g) ^ (n & 15)) << 3) + kk;
            outh[addr] = wh;
            outl[addr] = wl;
        }
    }
}

// ---- CSR build (same graph every call; rebuilt per call for harness purity) ----
__global__ __launch_bounds__(256) void hist_kernel(const int* __restrict__ dst,
                                                   int* __restrict__ counts) {
    int e = blockIdx.x * 256 + threadIdx.x;
    if (e < N_EDGES) atomicAdd(&counts[dst[e]], 1);
}

#define SCAN_BLOCKS 98  // 98*1024 >= 100000

__global__ __launch_bounds__(1024) void blockscan_kernel(const int* __restrict__ counts,
                                                         int* __restrict__ local,
                                                         int* __restrict__ bsums) {
    __shared__ int wsum[16];
    int tid = threadIdx.x, lane = tid & 63, wid = tid >> 6;
    int i = blockIdx.x * 1024 + tid;
    int v = (i < N_NODES) ? counts[i] : 0;
    int incl = v;
#pragma unroll
    for (int off = 1; off < 64; off <<= 1) {
        int u = __shfl_up(incl, off);
        if (lane >= off) incl += u;
    }
    if (lane == 63) wsum[wid] = incl;
    __syncthreads();
    if (wid == 0) {
        int s = (lane < 16) ? wsum[lane] : 0;
#pragma unroll
        for (int off = 1; off < 16; off <<= 1) {
            int u = __shfl_up(s, off);
            if (lane >= off) s += u;
        }
        if (lane < 16) wsum[lane] = s;  // inclusive wave sums
    }
    __syncthreads();
    int excl = ((wid == 0) ? 0 : wsum[wid - 1]) + incl - v;
    if (i < N_NODES) local[i] = excl;
    if (tid == 0) bsums[blockIdx.x] = wsum[15];
}

__global__ __launch_bounds__(1024) void fixup_kernel(const int* __restrict__ local,
                                                     const int* __restrict__ bsums,
                                                     int* __restrict__ offsets,
                                                     int* __restrict__ cursor) {
    __shared__ int sbase;
    int tid = threadIdx.x;
    if (tid < 64) {
        int s = 0;
        for (int j = tid; j < blockIdx.x; j += 64) s += bsums[j];
#pragma unroll
        for (int off = 32; off >= 1; off >>= 1) s += __shfl_xor(s, off);
        if (tid == 0) sbase = s;
    }
    __syncthreads();
    int base = sbase;
    int i = blockIdx.x * 1024 + tid;
    if (i < N_NODES) {
        int o = local[i] + base;
        offsets[i] = o;
        cursor[i] = o;
    }
    if (blockIdx.x == 0 && tid == 0) offsets[N_NODES] = N_EDGES;
}

__global__ __launch_bounds__(256) void fill_kernel(const int* __restrict__ src,
                                                   const int* __restrict__ dst,
                                                   int* __restrict__ cursor,
                                                   int* __restrict__ eidx) {
    int e = blockIdx.x * 256 + threadIdx.x;
    if (e < N_EDGES) {
        int pos = atomicAdd(&cursor[dst[e]], 1);
        eidx[pos] = src[e];
    }
}

// ---- aggregation: one wave per node; z[v] = h[v] + sum neighbors, 4-deep pipelined.
// Output: interleaved bf16 hi/lo planes, node stride 256 ushorts (hi at +0, lo at +128).
__global__ __launch_bounds__(256) void agg_kernel(const float* __restrict__ h,
                                                  const int* __restrict__ offsets,
                                                  const int* __restrict__ eidx,
                                                  ushortT* __restrict__ z) {
    int w = blockIdx.x * 4 + (threadIdx.x >> 6);  // node id; grid exact (25000 blocks)
    w = __builtin_amdgcn_readfirstlane(w);
    int lane = threadIdx.x & 63;
    const float* hp = h + lane * 2;
    int beg = offsets[w], end = offsets[w + 1];
    float2 acc = *(const float2*)(hp + (size_t)w * DIM);
    int i = beg, n = end - beg;
    while (n >= 4) {
        int s0 = eidx[i], s1 = eidx[i + 1], s2 = eidx[i + 2], s3 = eidx[i + 3];
        float2 v0 = *(const float2*)(hp + (size_t)s0 * DIM);
        float2 v1 = *(const float2*)(hp + (size_t)s1 * DIM);
        float2 v2 = *(const float2*)(hp + (size_t)s2 * DIM);
        float2 v3 = *(const float2*)(hp + (size_t)s3 * DIM);
        acc.x += (v0.x + v1.x) + (v2.x + v3.x);
        acc.y += (v0.y + v1.y) + (v2.y + v3.y);
        i += 4; n -= 4;
    }
    while (n > 0) {
        int s = eidx[i];
        float2 v = *(const float2*)(hp + (size_t)s * DIM);
        acc.x += v.x; acc.y += v.y;
        ++i; --n;
    }
    // split to bf16 hi/lo, store packed pairs
    ushortT hx = f2bf(acc.x), hy = f2bf(acc.y);
    float lx = acc.x - bf2f(hx), ly = acc.y - bf2f(hy);
    unsigned int hi = (unsigned int)hx | ((unsigned int)hy << 16);
    unsigned int lo = (unsigned int)f2bf(lx) | ((unsigned int)f2bf(ly) << 16);
    *(unsigned int*)(z + (size_t)w * 256 + lane * 2)       = hi;
    *(unsigned int*)(z + (size_t)w * 256 + 128 + lane * 2) = lo;
}

// GEMM: out = act(A @ W + bias), K=N=128, 3-term bf16-split (AhWh + AlWh + AhWl).
// A: interleaved bf16 hi/lo planes, row stride 256 ushorts (hi +0, lo +128).
// OMODE 0: write interleaved hi/lo bf16 (stride 256). OMODE 2: f32 (stride 128).
template <bool RELU, int OMODE>
__global__ __launch_bounds__(256) void gemm_kernel(const ushortT* __restrict__ A,
                                                   const ushortT* __restrict__ wt,  // hi at 0, lo at +16384
                                                   const float* __restrict__ bias,
                                                   void* __restrict__ out) {
    __shared__ ushortT WH[16384];
    __shared__ ushortT WL[16384];
    {   // copy pre-swizzled images: coalesced 16B, conflict-free LDS
        int t = threadIdx.x;
#pragma unroll
        for (int i = 0; i < 8; i++) {
            int idx = (t + i * 256) * 8;  // element index, 16B granule
            *(uint4v*)&WH[idx] = *(const uint4v*)&wt[idx];
            *(uint4v*)&WL[idx] = *(const uint4v*)&wt[16384 + idx];
        }
    }
    __syncthreads();

    int wid = threadIdx.x >> 6, lane = threadIdx.x & 63;
    int unit = blockIdx.x * 4 + wid;  // 32 rows per wave
    if (unit * 32 >= N_NODES) return;
    int row0 = unit * 32;
    int quad = lane >> 4;
    int col16 = lane & 15;

    float bia[8];
#pragma unroll
    for (int n = 0; n < 8; n++) bia[n] = bias[n * 16 + col16];

    float4v acc[2][8];
#pragma unroll
    for (int r = 0; r < 2; r++)
#pragma unroll
        for (int n = 0; n < 8; n++) acc[r][n] = (float4v)0.0f;

#pragma unroll
    for (int s = 0; s < 4; s++) {
        short8 bh[8], bl[8];
#pragma unroll
        for (int n = 0; n < 8; n++) {
            int addr = (n * 16 + col16) * 128 + (((s * 4 + quad) ^ col16) << 3);
            bh[n] = *(const short8*)&WH[addr];
            bl[n] = *(const short8*)&WL[addr];
        }
#pragma unroll
        for (int r = 0; r < 2; r++) {
            size_t arow = (size_t)(row0 + r * 16 + col16);
            const ushortT* ap = A + arow * 256 + s * 32 + quad * 8;
            short8 ah = *(const short8*)ap;
            short8 al = *(const short8*)(ap + 128);
#pragma unroll
            for (int n = 0; n < 8; n++) {
                acc[r][n] = __builtin_amdgcn_mfma_f32_16x16x32_bf16(ah, bh[n], acc[r][n], 0, 0, 0);
                acc[r][n] = __builtin_amdgcn_mfma_f32_16x16x32_bf16(al, bh[n], acc[r][n], 0, 0, 0);
                acc[r][n] = __builtin_amdgcn_mfma_f32_16x16x32_bf16(ah, bl[n], acc[r][n], 0, 0, 0);
            }
        }
    }

    // epilogue: C/D layout col=lane&15, row=quad*4+reg
#pragma unroll
    for (int r = 0; r < 2; r++) {
#pragma unroll
        for (int i = 0; i < 4; i++) {
            size_t row = (size_t)(row0 + r * 16 + quad * 4 + i);
#pragma unroll
            for (int n = 0; n < 8; n++) {
                float v = acc[r][n][i] + bia[n];
                if (RELU) v = v > 0.0f ? v : 0.0f;
                int col = n * 16 + col16;
                if constexpr (OMODE == 0) {
                    ushortT hi = f2bf(v);
                    ushortT lo = f2bf(v - bf2f(hi));
                    ((ushortT*)out)[row * 256 + col]       = hi;
                    ((ushortT*)out)[row * 256 + 128 + col] = lo;
                } else {
                    ((float*)out)[row * 128 + col] = v;
                }
            }
        }
    }
}

extern "C" void kernel_launch(void* const* d_in, const int* in_sizes, int n_in,
                              void* d_out, int out_size, void* d_ws, size_t ws_size,
                              hipStream_t stream) {
    const float* x  = (const float*)d_in[0];
    const int* src  = (const int*)d_in[1];
    const int* dst  = (const int*)d_in[2];
    const float* W1 = (const float*)d_in[3];
    const float* b1 = (const float*)d_in[4];
    const float* W2 = (const float*)d_in[5];
    const float* b2 = (const float*)d_in[6];

    ushortT* zbuf = (ushortT*)d_out;  // d_out doubles as interleaved bf16 z (51.2MB)

    char* ws = (char*)d_ws;
    ushortT* wt1    = (ushortT*)ws;                        // 64 KB (hi+lo)
    ushortT* wt2    = wt1 + 2 * 16384;                     // 64 KB
    int*     offs   = (int*)(ws + 131072);                 // 100001 ints
    int*     cursor = (int*)(ws + 531328);                 // 100000 ints
    int*     eidx   = (int*)(ws + 931328);                 // 600000 ints
    int*     local  = (int*)(ws + 3331328);                // 100000 ints
    int*     bsums  = (int*)(ws + 3731328);                // 98 ints
    ushortT* hidbuf = (ushortT*)(ws + 3731840);            // 51.2 MB interleaved hi/lo
    float*   hbuf   = (float*)(ws + 3731840 + 51200000);   // 51.2 MB f32
    // total ~106.2 MB

    dim3 blk(256);
    const int gEdge = (N_EDGES + 255) / 256;    // 2344
    const int gAgg  = N_NODES / 4;              // 25000 exact (1 wave/node)
    const int gGemm = (N_NODES / 32 + 3) / 4;   // 782

    prep_kernel<<<2, blk, 0, stream>>>(W1, W2, wt1);
    hipMemsetAsync(cursor, 0, N_NODES * sizeof(int), stream);
    hist_kernel<<<gEdge, blk, 0, stream>>>(dst, cursor);
    blockscan_kernel<<<SCAN_BLOCKS, 1024, 0, stream>>>(cursor, local, bsums);
    fixup_kernel<<<SCAN_BLOCKS, 1024, 0, stream>>>(local, bsums, offs, cursor);
    fill_kernel<<<gEdge, blk, 0, stream>>>(src, dst, cursor, eidx);

    // layer 0
    agg_kernel<<<gAgg, blk, 0, stream>>>(x, offs, eidx, zbuf);
    gemm_kernel<true, 0><<<gGemm, blk, 0, stream>>>(zbuf, wt1, b1, hidbuf);
    gemm_kernel<true, 2><<<gGemm, blk, 0, stream>>>(hidbuf, wt2, b2, hbuf);
    // layer 1
    agg_kernel<<<gAgg, blk, 0, stream>>>(hbuf, offs, eidx, zbuf);
    gemm_kernel<true, 0><<<gGemm, blk, 0, stream>>>(zbuf, wt1, b1, hidbuf);
    gemm_kernel<true, 2><<<gGemm, blk, 0, stream>>>(hidbuf, wt2, b2, hbuf);
    // layer 2 (final: no trailing relu); overwrites d_out with f32 result
    agg_kernel<<<gAgg, blk, 0, stream>>>(hbuf, offs, eidx, zbuf);
    gemm_kernel<true, 0><<<gGemm, blk, 0, stream>>>(zbuf, wt1, b1, hidbuf);
    gemm_kernel<false, 2><<<gGemm, blk, 0, stream>>>(hidbuf, wt2, b2, (float*)d_out);
}

// Round 7
// 475.198 us; speedup vs baseline: 3.6512x; 1.0039x over previous
//
#include <hip/hip_runtime.h>

#define N_NODES 100000
#define N_EDGES 600000
#define DIM 128

typedef unsigned short ushortT;
typedef __attribute__((ext_vector_type(8))) short short8;
typedef __attribute__((ext_vector_type(4))) float float4v;
typedef __attribute__((ext_vector_type(4))) unsigned int uint4v;

__device__ __forceinline__ float bf2f(ushortT h) {
    return __builtin_bit_cast(float, ((unsigned int)h) << 16);
}
__device__ __forceinline__ ushortT f2bf(float f) {  // RNE
    unsigned int x = __builtin_bit_cast(unsigned int, f);
    unsigned int r = (x + 0x7fffu + ((x >> 16) & 1u)) >> 16;
    return (ushortT)r;
}

// ---- prep: W (128x128 f32, row-major KxN) -> transposed+swizzled bf16 hi/lo images
// element (k,n) stored at  n*128 + (((k>>3) ^ (n&15))<<3) + (k&7)
__global__ __launch_bounds__(256) void prep_kernel(const float* __restrict__ W1,
                                                   const float* __restrict__ W2,
                                                   ushortT* __restrict__ wt) {
    const float* Wf = (blockIdx.x == 0) ? W1 : W2;
    ushortT* outh = wt + blockIdx.x * 2 * 16384;
    ushortT* outl = outh + 16384;
    int t = threadIdx.x;
#pragma unroll
    for (int i = 0; i < 16; i++) {
        int c = t + i * 256;            // 0..4095
        int k = c >> 5;
        int n0 = (c & 31) * 4;
        float4v w = *(const float4v*)(Wf + k * 128 + n0);
        int g = k >> 3, kk = k & 7;
#pragma unroll
        for (int j = 0; j < 4; j++) {
            int n = n0 + j;
            ushortT wh = f2bf(w[j]);
            ushortT wl = f2bf(w[j] - bf2f(wh));
            int addr = n * 128 + (((g) ^ (n & 15)) << 3) + kk;
            outh[addr] = wh;
            outl[addr] = wl;
        }
    }
}

// ---- CSR build (same graph every call; rebuilt per call for harness purity) ----
__global__ __launch_bounds__(256) void hist_kernel(const int* __restrict__ dst,
                                                   int* __restrict__ counts) {
    int e = blockIdx.x * 256 + threadIdx.x;
    if (e < N_EDGES) atomicAdd(&counts[dst[e]], 1);
}

#define SCAN_BLOCKS 98  // 98*1024 >= 100000

__global__ __launch_bounds__(1024) void blockscan_kernel(const int* __restrict__ counts,
                                                         int* __restrict__ local,
                                                         int* __restrict__ bsums) {
    __shared__ int wsum[16];
    int tid = threadIdx.x, lane = tid & 63, wid = tid >> 6;
    int i = blockIdx.x * 1024 + tid;
    int v = (i < N_NODES) ? counts[i] : 0;
    int incl = v;
#pragma unroll
    for (int off = 1; off < 64; off <<= 1) {
        int u = __shfl_up(incl, off);
        if (lane >= off) incl += u;
    }
    if (lane == 63) wsum[wid] = incl;
    __syncthreads();
    if (wid == 0) {
        int s = (lane < 16) ? wsum[lane] : 0;
#pragma unroll
        for (int off = 1; off < 16; off <<= 1) {
            int u = __shfl_up(s, off);
            if (lane >= off) s += u;
        }
        if (lane < 16) wsum[lane] = s;  // inclusive wave sums
    }
    __syncthreads();
    int excl = ((wid == 0) ? 0 : wsum[wid - 1]) + incl - v;
    if (i < N_NODES) local[i] = excl;
    if (tid == 0) bsums[blockIdx.x] = wsum[15];
}

__global__ __launch_bounds__(1024) void fixup_kernel(const int* __restrict__ local,
                                                     const int* __restrict__ bsums,
                                                     int* __restrict__ offsets,
                                                     int* __restrict__ cursor) {
    __shared__ int sbase;
    int tid = threadIdx.x;
    if (tid < 64) {
        int s = 0;
        for (int j = tid; j < blockIdx.x; j += 64) s += bsums[j];
#pragma unroll
        for (int off = 32; off >= 1; off >>= 1) s += __shfl_xor(s, off);
        if (tid == 0) sbase = s;
    }
    __syncthreads();
    int base = sbase;
    int i = blockIdx.x * 1024 + tid;
    if (i < N_NODES) {
        int o = local[i] + base;
        offsets[i] = o;
        cursor[i] = o;
    }
    if (blockIdx.x == 0 && tid == 0) offsets[N_NODES] = N_EDGES;
}

__global__ __launch_bounds__(256) void fill_kernel(const int* __restrict__ src,
                                                   const int* __restrict__ dst,
                                                   int* __restrict__ cursor,
                                                   int* __restrict__ eidx) {
    int e = blockIdx.x * 256 + threadIdx.x;
    if (e < N_EDGES) {
        int pos = atomicAdd(&cursor[dst[e]], 1);
        eidx[pos] = src[e];
    }
}

// ---- aggregation: one wave per node; z[v] = h[v] + sum neighbors.
// 8-deep batches with clamped duplicate indices (dups are L1 hits), masked accumulate.
// Output: interleaved bf16 hi/lo planes, node stride 256 ushorts (hi at +0, lo at +128).
__global__ __launch_bounds__(256) void agg_kernel(const float* __restrict__ h,
                                                  const int* __restrict__ offsets,
                                                  const int* __restrict__ eidx,
                                                  ushortT* __restrict__ z) {
    int w = blockIdx.x * 4 + (threadIdx.x >> 6);  // node id; grid exact (25000 blocks)
    w = __builtin_amdgcn_readfirstlane(w);
    int lane = threadIdx.x & 63;
    const float* hp = h + lane * 2;
    int beg = offsets[w], end = offsets[w + 1];
    int cnt = end - beg;
    float2 acc = *(const float2*)(hp + (size_t)w * DIM);
    for (int base = 0; base < cnt; base += 8) {
        int idx[8];
#pragma unroll
        for (int j = 0; j < 8; j++) {
            int q = base + j;
            if (q > cnt - 1) q = cnt - 1;
            idx[j] = eidx[beg + q];
        }
        float2 v[8];
#pragma unroll
        for (int j = 0; j < 8; j++) v[j] = *(const float2*)(hp + (size_t)idx[j] * DIM);
        int rem = cnt - base;  // wave-uniform
#pragma unroll
        for (int j = 0; j < 8; j++)
            if (j < rem) { acc.x += v[j].x; acc.y += v[j].y; }
    }
    // split to bf16 hi/lo, store packed pairs
    ushortT hx = f2bf(acc.x), hy = f2bf(acc.y);
    float lx = acc.x - bf2f(hx), ly = acc.y - bf2f(hy);
    unsigned int hi = (unsigned int)hx | ((unsigned int)hy << 16);
    unsigned int lo = (unsigned int)f2bf(lx) | ((unsigned int)f2bf(ly) << 16);
    *(unsigned int*)(z + (size_t)w * 256 + lane * 2)       = hi;
    *(unsigned int*)(z + (size_t)w * 256 + 128 + lane * 2) = lo;
}

// GEMM: out = act(A @ W + bias), K=N=128, 3-term bf16-split (AhWh + AlWh + AhWl).
// A: interleaved bf16 hi/lo planes, row stride 256 ushorts (hi +0, lo +128).
// All 16 A-fragments prefetched before W staging: one latency exposure per wave,
// overlapped with the LDS fill + barrier. K-loop is LDS reads + MFMA only.
// OMODE 0: write interleaved hi/lo bf16 (stride 256). OMODE 2: f32 (stride 128).
template <bool RELU, int OMODE>
__global__ __launch_bounds__(256) void gemm_kernel(const ushortT* __restrict__ A,
                                                   const ushortT* __restrict__ wt,  // hi at 0, lo at +16384
                                                   const float* __restrict__ bias,
                                                   void* __restrict__ out) {
    __shared__ ushortT WH[16384];
    __shared__ ushortT WL[16384];

    int t = threadIdx.x;
    int wid = t >> 6, lane = t & 63;
    int unit = blockIdx.x * 4 + wid;  // 32 rows per wave
    int row0 = unit * 32;
    int quad = lane >> 4;
    int col16 = lane & 15;
    bool active = row0 < N_NODES;

    // ---- A prefetch: 16 independent 16B loads, issued before staging ----
    short8 ah[4][2], al[4][2];
    if (active) {
#pragma unroll
        for (int s = 0; s < 4; s++)
#pragma unroll
            for (int r = 0; r < 2; r++) {
                const ushortT* ap = A + (size_t)(row0 + r * 16 + col16) * 256 + s * 32 + quad * 8;
                ah[s][r] = *(const short8*)ap;
                al[s][r] = *(const short8*)(ap + 128);
            }
    }

    // ---- stage pre-swizzled W images: coalesced 16B, conflict-free LDS ----
#pragma unroll
    for (int i = 0; i < 8; i++) {
        int idx = (t + i * 256) * 8;  // element index, 16B granule
        *(uint4v*)&WH[idx] = *(const uint4v*)&wt[idx];
        *(uint4v*)&WL[idx] = *(const uint4v*)&wt[16384 + idx];
    }
    __syncthreads();
    if (!active) return;

    float bia[8];
#pragma unroll
    for (int n = 0; n < 8; n++) bia[n] = bias[n * 16 + col16];

    float4v acc[2][8];
#pragma unroll
    for (int r = 0; r < 2; r++)
#pragma unroll
        for (int n = 0; n < 8; n++) acc[r][n] = (float4v)0.0f;

#pragma unroll
    for (int s = 0; s < 4; s++) {
        short8 bh[8], bl[8];
#pragma unroll
        for (int n = 0; n < 8; n++) {
            int addr = (n * 16 + col16) * 128 + (((s * 4 + quad) ^ col16) << 3);
            bh[n] = *(const short8*)&WH[addr];
            bl[n] = *(const short8*)&WL[addr];
        }
#pragma unroll
        for (int r = 0; r < 2; r++) {
#pragma unroll
            for (int n = 0; n < 8; n++) {
                acc[r][n] = __builtin_amdgcn_mfma_f32_16x16x32_bf16(ah[s][r], bh[n], acc[r][n], 0, 0, 0);
                acc[r][n] = __builtin_amdgcn_mfma_f32_16x16x32_bf16(al[s][r], bh[n], acc[r][n], 0, 0, 0);
                acc[r][n] = __builtin_amdgcn_mfma_f32_16x16x32_bf16(ah[s][r], bl[n], acc[r][n], 0, 0, 0);
            }
        }
    }

    // epilogue: C/D layout col=lane&15, row=quad*4+reg
#pragma unroll
    for (int r = 0; r < 2; r++) {
#pragma unroll
        for (int i = 0; i < 4; i++) {
            size_t row = (size_t)(row0 + r * 16 + quad * 4 + i);
#pragma unroll
            for (int n = 0; n < 8; n++) {
                float v = acc[r][n][i] + bia[n];
                if (RELU) v = v > 0.0f ? v : 0.0f;
                int col = n * 16 + col16;
                if constexpr (OMODE == 0) {
                    ushortT hi = f2bf(v);
                    ushortT lo = f2bf(v - bf2f(hi));
                    ((ushortT*)out)[row * 256 + col]       = hi;
                    ((ushortT*)out)[row * 256 + 128 + col] = lo;
                } else {
                    ((float*)out)[row * 128 + col] = v;
                }
            }
        }
    }
}

extern "C" void kernel_launch(void* const* d_in, const int* in_sizes, int n_in,
                              void* d_out, int out_size, void* d_ws, size_t ws_size,
                              hipStream_t stream) {
    const float* x  = (const float*)d_in[0];
    const int* src  = (const int*)d_in[1];
    const int* dst  = (const int*)d_in[2];
    const float* W1 = (const float*)d_in[3];
    const float* b1 = (const float*)d_in[4];
    const float* W2 = (const float*)d_in[5];
    const float* b2 = (const float*)d_in[6];

    ushortT* zbuf = (ushortT*)d_out;  // d_out doubles as interleaved bf16 z (51.2MB)

    char* ws = (char*)d_ws;
    ushortT* wt1    = (ushortT*)ws;                        // 64 KB (hi+lo)
    ushortT* wt2    = wt1 + 2 * 16384;                     // 64 KB
    int*     offs   = (int*)(ws + 131072);                 // 100001 ints
    int*     cursor = (int*)(ws + 531328);                 // 100000 ints
    int*     eidx   = (int*)(ws + 931328);                 // 600000 ints
    int*     local  = (int*)(ws + 3331328);                // 100000 ints
    int*     bsums  = (int*)(ws + 3731328);                // 98 ints
    ushortT* hidbuf = (ushortT*)(ws + 3731840);            // 51.2 MB interleaved hi/lo
    float*   hbuf   = (float*)(ws + 3731840 + 51200000);   // 51.2 MB f32
    // total ~106.2 MB

    dim3 blk(256);
    const int gEdge = (N_EDGES + 255) / 256;    // 2344
    const int gAgg  = N_NODES / 4;              // 25000 exact (1 wave/node)
    const int gGemm = (N_NODES / 32 + 3) / 4;   // 782

    prep_kernel<<<2, blk, 0, stream>>>(W1, W2, wt1);
    hipMemsetAsync(cursor, 0, N_NODES * sizeof(int), stream);
    hist_kernel<<<gEdge, blk, 0, stream>>>(dst, cursor);
    blockscan_kernel<<<SCAN_BLOCKS, 1024, 0, stream>>>(cursor, local, bsums);
    fixup_kernel<<<SCAN_BLOCKS, 1024, 0, stream>>>(local, bsums, offs, cursor);
    fill_kernel<<<gEdge, blk, 0, stream>>>(src, dst, cursor, eidx);

    // layer 0
    agg_kernel<<<gAgg, blk, 0, stream>>>(x, offs, eidx, zbuf);
    gemm_kernel<true, 0><<<gGemm, blk, 0, stream>>>(zbuf, wt1, b1, hidbuf);
    gemm_kernel<true, 2><<<gGemm, blk, 0, stream>>>(hidbuf, wt2, b2, hbuf);
    // layer 1
    agg_kernel<<<gAgg, blk, 0, stream>>>(hbuf, offs, eidx, zbuf);
    gemm_kernel<true, 0><<<gGemm, blk, 0, stream>>>(zbuf, wt1, b1, hidbuf);
    gemm_kernel<true, 2><<<gGemm, blk, 0, stream>>>(hidbuf, wt2, b2, hbuf);
    // layer 2 (final: no trailing relu); overwrites d_out with f32 result
    agg_kernel<<<gAgg, blk, 0, stream>>>(hbuf, offs, eidx, zbuf);
    gemm_kernel<true, 0><<<gGemm, blk, 0, stream>>>(zbuf, wt1, b1, hidbuf);
    gemm_kernel<false, 2><<<gGemm, blk, 0, stream>>>(hidbuf, wt2, b2, (float*)d_out);
}